// Round 1
// baseline (351.222 us; speedup 1.0000x reference)
//
#include <hip/hip_runtime.h>

// conv_transpose2d(x(4,256,128,128), w(256,256,4,4) block-diagonal, stride=2)
// -> out (4,256,258,258). Depthwise: off-diagonal w entries are exactly 0.0,
// so using only w[c][c] is bit-identical to the dense conv.
//
// R3 design: one thread computes a 4-row x 8-col output tile (TWO adjacent
// cell-rows ci0=2ri, ci1=2ri+1, 4 cells wide). This needs only 3 input rows
// (2ri-1, 2ri, 2ri+1) -- the middle row is shared between the two cell-rows,
// vs 2 rows per cell-row in the previous 2x8-tile version. Thread count
// halves (4.45M -> 2.2M), x-load traffic drops 25%, per-output address and
// bounds work halves, and per-thread ILP doubles.
//
// Filter w[c][c] is loaded with uniform (blockIdx-only) indices -> compiler
// emits s_load into SGPRs: no LDS, no __syncthreads. x loads are float4 + one
// halo scalar per row; edges handled by clamp+zero (branchless). Even output
// rows are 16B-aligned (row pitch 258 floats => odd rows are 8B-aligned,
// stored as float2/float4/float2).

#define CCH    256
#define HIN    128
#define WIN    128
#define HOUT   258
#define WOUT   258
#define GRP    33            // groups of 4 cells per cell-row (last has 1 cell)
#define RPAIRS 65            // cell-row pairs (2ri, 2ri+1); ri=64 has only cell-row 128

__global__ __launch_bounds__(256) void upconv2x_kernel(
    const float* __restrict__ x,
    const float* __restrict__ w,
    float* __restrict__ out)
{
    const int slice = blockIdx.y;           // n*CCH + c
    const int c = slice & (CCH - 1);

    // Uniform index -> scalar loads into SGPRs (no LDS, no sync)
    const float* __restrict__ wf = w + ((size_t)c * CCH + c) * 16;
    float f[16];
#pragma unroll
    for (int i = 0; i < 16; ++i) f[i] = wf[i];

    const int t = blockIdx.x * blockDim.x + threadIdx.x;
    if (t >= RPAIRS * GRP) return;
    const int ri  = t / GRP;
    const int g   = t - ri * GRP;
    const int cj0 = g * 4;                  // first cell col of this group

    const int  ci0 = 2 * ri;                // first cell-row: 0..128
    const bool lo  = (ri < 64);             // x rows 2ri,2ri+1 in-bounds AND cell-row ci1 exists
    const bool va  = (ci0 > 0);             // x row 2ri-1 in-bounds
    const bool g32 = (cj0 == 128);          // tail group: single cell cj=128
    const int  iya = va ? (ci0 - 1) : 0;
    const int  iyb = lo ? ci0       : (HIN - 1);
    const int  iyc = lo ? (ci0 + 1) : 0;
    const int  cjc = g32 ? 124 : cj0;       // keep float4 load in-bounds
    const int  hj  = (cj0 > 0) ? (cj0 - 1) : 0;

    const float* __restrict__ xs = x + (size_t)slice * (HIN * WIN);
    const float* __restrict__ ba = xs + (size_t)iya * WIN;  // x[ci0-1]
    const float* __restrict__ bb = xs + (size_t)iyb * WIN;  // x[ci0]
    const float* __restrict__ bc = xs + (size_t)iyc * WIN;  // x[ci0+1]

    float4 Aa = *(const float4*)(ba + cjc);
    float4 Ab = *(const float4*)(bb + cjc);
    float4 Ac = *(const float4*)(bc + cjc);
    float  ha = ba[hj], hb = bb[hj], hc = bc[hj];

    if (!va) { Aa = make_float4(0.f,0.f,0.f,0.f); ha = 0.f; }
    if (!lo) { Ab = make_float4(0.f,0.f,0.f,0.f); hb = 0.f;
               Ac = make_float4(0.f,0.f,0.f,0.f); hc = 0.f; }
    if (g32) { Aa = make_float4(0.f,0.f,0.f,0.f);
               Ab = make_float4(0.f,0.f,0.f,0.f);
               Ac = make_float4(0.f,0.f,0.f,0.f); }
    if (cj0 == 0) { ha = 0.f; hb = 0.f; hc = 0.f; }

    // cols cj0-1..cj0+3 for the three input rows
    const float ca[5] = { ha, Aa.x, Aa.y, Aa.z, Aa.w };
    const float cb[5] = { hb, Ab.x, Ab.y, Ab.z, Ab.w };
    const float cc[5] = { hc, Ac.x, Ac.y, Ac.z, Ac.w };

    // Cell-row ci:  out[2ci][2cj+dw]   = x[ci]*f[dw]   + x[ci][cj-1]*f[dw+2]
    //                                  + x[ci-1]*f[8+dw] + x[ci-1][cj-1]*f[10+dw]
    //               out[2ci+1][2cj+dw] = same with f[4..7], f[12..15]
    float e0[8], o0[8], e1[8], o1[8];
#pragma unroll
    for (int k = 0; k < 4; ++k) {
        const float pa = ca[k + 1], ma = ca[k];
        const float pb = cb[k + 1], mb = cb[k];
        const float pc = cc[k + 1], mc = cc[k];
        // cell-row ci0 = 2ri: p-row = x[ci0], m-row = x[ci0-1]
        e0[2*k]   = pb*f[0] + mb*f[2]  + pa*f[8]  + ma*f[10];
        e0[2*k+1] = pb*f[1] + mb*f[3]  + pa*f[9]  + ma*f[11];
        o0[2*k]   = pb*f[4] + mb*f[6]  + pa*f[12] + ma*f[14];
        o0[2*k+1] = pb*f[5] + mb*f[7]  + pa*f[13] + ma*f[15];
        // cell-row ci1 = 2ri+1: p-row = x[ci1], m-row = x[ci0]
        e1[2*k]   = pc*f[0] + mc*f[2]  + pb*f[8]  + mb*f[10];
        e1[2*k+1] = pc*f[1] + mc*f[3]  + pb*f[9]  + mb*f[11];
        o1[2*k]   = pc*f[4] + mc*f[6]  + pb*f[12] + mb*f[14];
        o1[2*k+1] = pc*f[5] + mc*f[7]  + pb*f[13] + mb*f[15];
    }

    float* __restrict__ os = out + (size_t)slice * (HOUT * WOUT);
    float* p0 = os + (size_t)(4 * ri) * WOUT + 2 * cj0;  // 16B-aligned (1032ri + even elems, ≡0 mod 4)
    float* p1 = p0 + WOUT;                               // 8B-aligned only

    if (!g32) {
        *(float4*)(p0)     = make_float4(e0[0], e0[1], e0[2], e0[3]);
        *(float4*)(p0 + 4) = make_float4(e0[4], e0[5], e0[6], e0[7]);
        *(float2*)(p1)     = make_float2(o0[0], o0[1]);
        *(float4*)(p1 + 2) = make_float4(o0[2], o0[3], o0[4], o0[5]);
        *(float2*)(p1 + 6) = make_float2(o0[6], o0[7]);
        if (lo) {
            float* p2 = p1 + WOUT;                       // 16B-aligned
            float* p3 = p2 + WOUT;
            *(float4*)(p2)     = make_float4(e1[0], e1[1], e1[2], e1[3]);
            *(float4*)(p2 + 4) = make_float4(e1[4], e1[5], e1[6], e1[7]);
            *(float2*)(p3)     = make_float2(o1[0], o1[1]);
            *(float4*)(p3 + 2) = make_float4(o1[2], o1[3], o1[4], o1[5]);
            *(float2*)(p3 + 6) = make_float2(o1[6], o1[7]);
        }
    } else {
        // tail: only cell cj=128 -> out cols 256,257
        *(float2*)(p0) = make_float2(e0[0], e0[1]);
        *(float2*)(p1) = make_float2(o0[0], o0[1]);
        if (lo) {
            float* p2 = p1 + WOUT;
            float* p3 = p2 + WOUT;
            *(float2*)(p2) = make_float2(e1[0], e1[1]);
            *(float2*)(p3) = make_float2(o1[0], o1[1]);
        }
    }
}

extern "C" void kernel_launch(void* const* d_in, const int* in_sizes, int n_in,
                              void* d_out, int out_size, void* d_ws, size_t ws_size,
                              hipStream_t stream) {
    const float* x = (const float*)d_in[0];
    const float* w = (const float*)d_in[1];
    float* out = (float*)d_out;

    const int work = RPAIRS * GRP;                   // 2145 threads per slice
    dim3 block(256);
    dim3 grid((work + 255) / 256, 4 * CCH);          // 9 x 1024
    upconv2x_kernel<<<grid, block, 0, stream>>>(x, w, out);
}

// Round 2
// 344.886 us; speedup vs baseline: 1.0184x; 1.0184x over previous
//
#include <hip/hip_runtime.h>

// conv_transpose2d(x(4,256,128,128), w(256,256,4,4) block-diagonal, stride=2)
// -> out (4,256,258,258). Depthwise: off-diagonal w entries are exactly 0.0,
// so using only w[c][c] is bit-identical to the dense conv.
//
// R4 design: store-coalescing-first. Lane j of a wave owns output cols
// 4j..4j+3 of a full output row: one float4 store per row per lane means a
// wave's single store instruction covers a fully dense, contiguous 1024 B
// span (vs 50%-dense strided stores in R2/R3). The 2 tail cols (256,257)
// are a lane-63-predicated float2.
//
// Each wave marches down PERB=17 consecutive output row-pairs (cell-rows ci)
// of one slice, carrying input rows x[ci-1], x[ci] in registers: each input
// row is loaded once (coalesced float2 per lane = 512 B/wave) and the left
// halo col comes from __shfl_up. Filter w[c][c] is loaded with uniform
// indices -> SGPRs; no LDS, no __syncthreads.

#define CCH   256
#define HIN   128
#define WIN   128
#define HOUT  258
#define WOUT  258
#define PAIRS 129            // cell-rows ci in [0,128]; out rows 2ci, 2ci+1
#define PERB  17             // row-pairs per wave band (8 bands: 7x17 + 1x10)

__global__ __launch_bounds__(256) void upconv2x_kernel(
    const float* __restrict__ x,
    const float* __restrict__ w,
    float* __restrict__ out)
{
    const int slice = blockIdx.y;             // n*CCH + c
    const int c = slice & (CCH - 1);

    // Uniform index -> scalar loads into SGPRs (no LDS, no sync)
    const float* __restrict__ wf = w + ((size_t)c * CCH + c) * 16;
    float f[16];
#pragma unroll
    for (int i = 0; i < 16; ++i) f[i] = wf[i];

    const int wave = threadIdx.x >> 6;
    const int lane = threadIdx.x & 63;
    const int band = (blockIdx.x << 2) + wave;     // 0..7
    const int c0 = band * PERB;
    const int c1 = (c0 + PERB < PAIRS) ? (c0 + PERB) : PAIRS;

    const float* __restrict__ xs = x + (size_t)slice * (HIN * WIN);

    // Registers for input rows at cols {2j-1, 2j, 2j+1}:
    //   p* = x[ci-1], c* = x[ci], n* = x[ci+1] (prefetch)
    float pm = 0.f, p0v = 0.f, p1v = 0.f;
    float cm = 0.f, c0v = 0.f, c1v = 0.f;
    if (c0 > 0) {                                  // wave-uniform branch
        const float2 v = *(const float2*)(xs + (size_t)(c0 - 1) * WIN + 2 * lane);
        p0v = v.x; p1v = v.y;
        pm = __shfl_up(p1v, 1); if (lane == 0) pm = 0.f;
    }
    {   // c0 <= 119 < HIN always
        const float2 v = *(const float2*)(xs + (size_t)c0 * WIN + 2 * lane);
        c0v = v.x; c1v = v.y;
        cm = __shfl_up(c1v, 1); if (lane == 0) cm = 0.f;
    }

    float* __restrict__ pr = out + (size_t)slice * ((size_t)HOUT * WOUT)
                           + (size_t)(2 * c0) * WOUT + 4 * lane;

    for (int ci = c0; ci < c1; ++ci) {
        // prefetch next input row (wave-uniform condition)
        float nm = 0.f, n0v = 0.f, n1v = 0.f;
        if ((ci + 1 < c1) && (ci + 1 < HIN)) {
            const float2 v = *(const float2*)(xs + (size_t)(ci + 1) * WIN + 2 * lane);
            n0v = v.x; n1v = v.y;
            nm = __shfl_up(n1v, 1); if (lane == 0) nm = 0.f;
        }

        // out[2ci][2cj+dw]   = x[ci][cj]*f[dw]   + x[ci][cj-1]*f[dw+2]
        //                    + x[ci-1][cj]*f[8+dw] + x[ci-1][cj-1]*f[10+dw]
        // lane j covers cj = 2j (cols 4j,4j+1) and cj = 2j+1 (cols 4j+2,4j+3)
        float4 r;
        r.x = c0v*f[0] + cm *f[2] + p0v*f[8]  + pm *f[10];
        r.y = c0v*f[1] + cm *f[3] + p0v*f[9]  + pm *f[11];
        r.z = c1v*f[0] + c0v*f[2] + p1v*f[8]  + p0v*f[10];
        r.w = c1v*f[1] + c0v*f[3] + p1v*f[9]  + p0v*f[11];
        *(float4*)pr = r;                        // dense 1024 B per wave
        if (lane == 63)                          // cols 256,257: cj=128, only m-terms
            *(float2*)(pr + 4) = make_float2(c1v*f[2] + p1v*f[10],
                                             c1v*f[3] + p1v*f[11]);

        r.x = c0v*f[4] + cm *f[6] + p0v*f[12] + pm *f[14];
        r.y = c0v*f[5] + cm *f[7] + p0v*f[13] + pm *f[15];
        r.z = c1v*f[4] + c0v*f[6] + p1v*f[12] + p0v*f[14];
        r.w = c1v*f[5] + c0v*f[7] + p1v*f[13] + p0v*f[15];
        *(float4*)(pr + WOUT) = r;
        if (lane == 63)
            *(float2*)(pr + WOUT + 4) = make_float2(c1v*f[6] + p1v*f[14],
                                                    c1v*f[7] + p1v*f[15]);

        // rotate rows: prev <- cur <- next
        pm = cm; p0v = c0v; p1v = c1v;
        cm = nm; c0v = n0v; c1v = n1v;
        pr += 2 * WOUT;
    }
}

extern "C" void kernel_launch(void* const* d_in, const int* in_sizes, int n_in,
                              void* d_out, int out_size, void* d_ws, size_t ws_size,
                              hipStream_t stream) {
    const float* x = (const float*)d_in[0];
    const float* w = (const float*)d_in[1];
    float* out = (float*)d_out;

    dim3 block(256);                 // 4 waves = bands 4b..4b+3 of one slice
    dim3 grid(2, 4 * CCH);           // 2 half-slices x 1024 slices
    upconv2x_kernel<<<grid, block, 0, stream>>>(x, w, out);
}